// Round 16
// baseline (1106.848 us; speedup 1.0000x reference)
//
#include <hip/hip_runtime.h>
#include <hip/hip_bf16.h>
#include <math.h>

#define D_EMB 768
#define NPATCH 16
#define NTOK 512
#define NHEAD 12
#define HDIM 64
#define NLAYER 6
#define DFF 3072
#define BATCH 8
#define MTOK (BATCH * NTOK)   // 4096 rows

typedef __attribute__((ext_vector_type(8))) short bf16x8;
typedef __attribute__((ext_vector_type(8))) ushort u16x8;
typedef __attribute__((ext_vector_type(4))) float f32x4;

__device__ __forceinline__ float bf2f(ushort s) {
    unsigned u = ((unsigned)s) << 16;
    return __builtin_bit_cast(float, u);
}
__device__ __forceinline__ ushort f2bf(float f) {
    unsigned u = __builtin_bit_cast(unsigned, f);
    unsigned r = (u + 0x7FFFu + ((u >> 16) & 1u)) >> 16;   // RNE
    return (ushort)r;
}

// ---------------- fp32 -> bf16 convert, 4 segments, 4 elems/thread (measured
// fastest form, R13), grid-stride per G11. counts in UNITS OF 4 ELEMENTS.
__global__ __launch_bounds__(256)
void f2bf4_kernel(const float* __restrict__ s0, ushort* __restrict__ d0, int n0,
                  const float* __restrict__ s1, ushort* __restrict__ d1, int n1,
                  const float* __restrict__ s2, ushort* __restrict__ d2, int n2,
                  const float* __restrict__ s3, ushort* __restrict__ d3, int n3)
{
    int tot = n0 + n1 + n2 + n3;
    int stride = gridDim.x * 256;
    for (int i = blockIdx.x * 256 + threadIdx.x; i < tot; i += stride) {
        const float* s; ushort* d; int off;
        if (i < n0)                { s = s0; d = d0; off = i; }
        else if (i < n0 + n1)      { s = s1; d = d1; off = i - n0; }
        else if (i < n0 + n1 + n2) { s = s2; d = d2; off = i - n0 - n1; }
        else                       { s = s3; d = d3; off = i - n0 - n1 - n2; }
        float4 v = *(const float4*)(s + (size_t)off * 4);
        ushort4 o;
        o.x = f2bf(v.x); o.y = f2bf(v.y); o.z = f2bf(v.z); o.w = f2bf(v.w);
        *(ushort4*)(d + (size_t)off * 4) = o;
    }
}

// ---------------- patch embed
__global__ __launch_bounds__(256)
void patch_embed_kernel(const float* __restrict__ x, const float* __restrict__ pw,
                        const float* __restrict__ pb, const float* __restrict__ pe,
                        float* __restrict__ z)
{
    int bn = blockIdx.x;            // 0..4095
    int b = bn >> 9, n = bn & 511;
    __shared__ float xs[NPATCH];
    int t = threadIdx.x;
    if (t < NPATCH) xs[t] = x[(size_t)b * 8192 + n * NPATCH + t];
    __syncthreads();
    for (int d = t; d < D_EMB; d += 256) {
        float acc = pb[d] + pe[(size_t)n * D_EMB + d];
        const float* w = pw + (size_t)d * NPATCH;
        #pragma unroll
        for (int p = 0; p < NPATCH; ++p) acc += xs[p] * w[p];
        z[(size_t)bn * D_EMB + d] = acc;
    }
}

// ---------------- block reduce (256 threads = 4 waves)
__device__ __forceinline__ float block_reduce_sum_256(float v)
{
    __shared__ float lds[4];
    #pragma unroll
    for (int o = 32; o > 0; o >>= 1) v += __shfl_xor(v, o);
    int lane = threadIdx.x & 63, wid = threadIdx.x >> 6;
    __syncthreads();
    if (lane == 0) lds[wid] = v;
    __syncthreads();
    return lds[0] + lds[1] + lds[2] + lds[3];
}

__device__ __forceinline__ void store_val(float* p, float v)  { *p = v; }
__device__ __forceinline__ void store_val(ushort* p, float v) { *p = f2bf(v); }

// ---------------- layernorm over D=768, one block (256 thr) per row
template<typename OT>
__global__ __launch_bounds__(256)
void ln_kernel(const float* __restrict__ x, const float* __restrict__ g,
               const float* __restrict__ bta, OT* __restrict__ y)
{
    int row = blockIdx.x;
    const float* xr = x + (size_t)row * D_EMB;
    int t = threadIdx.x;
    float vals[3];
    float s = 0.f;
    #pragma unroll
    for (int i = 0; i < 3; ++i) { vals[i] = xr[t + i * 256]; s += vals[i]; }
    float mean = block_reduce_sum_256(s) * (1.0f / D_EMB);
    float ss = 0.f;
    #pragma unroll
    for (int i = 0; i < 3; ++i) { float d = vals[i] - mean; ss += d * d; }
    float var = block_reduce_sum_256(ss) * (1.0f / D_EMB);
    float rstd = rsqrtf(var + 1e-5f);
    #pragma unroll
    for (int i = 0; i < 3; ++i) {
        int d = t + i * 256;
        store_val(y + (size_t)row * D_EMB + d, (vals[i] - mean) * rstd * g[d] + bta[d]);
    }
}

// ---------------- fused split-K reduce + residual + layernorm
template<typename OT>
__global__ __launch_bounds__(256)
void reduce_ln_kernel(const float* __restrict__ pbuf, float* __restrict__ z,
                      const float* __restrict__ g, const float* __restrict__ bta,
                      OT* __restrict__ y)
{
    int row = blockIdx.x;
    int t = threadIdx.x;
    const float* p0 = pbuf + (size_t)row * D_EMB;
    const float* p1 = pbuf + (size_t)MTOK * D_EMB + (size_t)row * D_EMB;
    float* zr = z + (size_t)row * D_EMB;
    float vals[3];
    float s = 0.f;
    #pragma unroll
    for (int i = 0; i < 3; ++i) {
        int d = t + i * 256;
        float v = zr[d] + p0[d] + p1[d];
        vals[i] = v;
        zr[d] = v;
        s += v;
    }
    float mean = block_reduce_sum_256(s) * (1.0f / D_EMB);
    float ss = 0.f;
    #pragma unroll
    for (int i = 0; i < 3; ++i) { float d = vals[i] - mean; ss += d * d; }
    float var = block_reduce_sum_256(ss) * (1.0f / D_EMB);
    float rstd = rsqrtf(var + 1e-5f);
    #pragma unroll
    for (int i = 0; i < 3; ++i) {
        int d = t + i * 256;
        store_val(y + (size_t)row * D_EMB + d, (vals[i] - mean) * rstd * g[d] + bta[d]);
    }
}

// ---------------- bf16 MFMA GEMM (R15 form: strength-reduced addresses)
// 64x128 tile, BK=64, 4 waves, global_load_lds w=16, rule-21 XOR swizzle,
// R6 M-slice XCD map, 2-buffer issue-early prefetch, ping-pong unroll.
// EPI: 0 = none, 1 = exact gelu, 2 = add residual(fp32)
// SPLITK: grid.z = K-chunks; A/W advance by bz*K, C by bz*(gy*64)*N partials.
#define STAGE64(buf)                                                               \
    {                                                                              \
        _Pragma("unroll")                                                          \
        for (int j = 0; j < 2; ++j) {                                              \
            __builtin_amdgcn_global_load_lds(                                      \
                (const __attribute__((address_space(1))) unsigned int*)gA[j],      \
                (__attribute__((address_space(3))) unsigned int*)&As[buf][dA[j]],  \
                16, 0, 0);                                                         \
            gA[j] += 64;                                                           \
        }                                                                          \
        _Pragma("unroll")                                                          \
        for (int j = 0; j < 4; ++j) {                                              \
            __builtin_amdgcn_global_load_lds(                                      \
                (const __attribute__((address_space(1))) unsigned int*)gB[j],      \
                (__attribute__((address_space(3))) unsigned int*)&Bs[buf][dB[j]],  \
                16, 0, 0);                                                         \
            gB[j] += 64;                                                           \
        }                                                                          \
    }

#define COMPUTE64(buf)                                                             \
    {                                                                              \
        bf16x8 a0[4], a1[4], b0[2], b1[2];                                         \
        _Pragma("unroll")                                                          \
        for (int m = 0; m < 4; ++m) {                                              \
            a0[m] = *(const bf16x8*)(&As[buf][rA[m] + x0]);                        \
            a1[m] = *(const bf16x8*)(&As[buf][rA[m] + x1]);                        \
        }                                                                          \
        _Pragma("unroll")                                                          \
        for (int n = 0; n < 2; ++n) {                                              \
            b0[n] = *(const bf16x8*)(&Bs[buf][rB[n] + x0]);                        \
            b1[n] = *(const bf16x8*)(&Bs[buf][rB[n] + x1]);                        \
        }                                                                          \
        _Pragma("unroll")                                                          \
        for (int m = 0; m < 4; ++m)                                                \
            _Pragma("unroll")                                                      \
            for (int n = 0; n < 2; ++n)                                            \
                acc[m][n] = __builtin_amdgcn_mfma_f32_16x16x32_bf16(a0[m], b0[n], acc[m][n], 0, 0, 0); \
        _Pragma("unroll")                                                          \
        for (int m = 0; m < 4; ++m)                                                \
            _Pragma("unroll")                                                      \
            for (int n = 0; n < 2; ++n)                                            \
                acc[m][n] = __builtin_amdgcn_mfma_f32_16x16x32_bf16(a1[m], b1[n], acc[m][n], 0, 0, 0); \
    }

template<int EPI, typename OT, bool SPLITK>
__global__ __launch_bounds__(256)
void mfma_gemm(const ushort* __restrict__ A, const ushort* __restrict__ W,
               OT* __restrict__ C, const float* __restrict__ res,
               int N, int K, int lda)
{
    __shared__ ushort As[2][64 * 64];
    __shared__ ushort Bs[2][128 * 64];

    int gx = gridDim.x, gy = gridDim.y;
    int bx = blockIdx.x, by = blockIdx.y;
    int bz = SPLITK ? blockIdx.z : 0;
    if ((gy & 7) == 0) {
        int flat = bx + gx * (by + gy * bz);
        int xcd = flat & 7, j = flat >> 3;
        int ry = gy >> 3;
        by = xcd * ry + (j % ry);
        int rem = j / ry;
        bx = rem % gx;
        bz = rem / gx;
    }
    int bm = by * 64, bn = bx * 128;

    const ushort* Ab = A + (size_t)bz * K;
    const ushort* Wb = W + (size_t)bz * K;
    OT* Cb = C + (SPLITK ? (size_t)bz * ((size_t)gy * 64) * N : 0);

    int tid = threadIdx.x;
    int w = tid >> 6, l = tid & 63;
    int lr = l & 15, lg = l >> 4;
    f32x4 acc[4][2] = {};

    int srow = w * 8 + (l >> 3);
    int pcol = l & 7;
    int lcol8 = (pcol ^ (srow & 7)) << 3;

    const ushort* gA[2]; const ushort* gB[4];
    int dA[2], dB[4];
    #pragma unroll
    for (int j = 0; j < 2; ++j) {
        gA[j] = Ab + (size_t)(bm + j * 32 + srow) * lda + lcol8;
        dA[j] = (j * 32 + srow) * 64 + (pcol << 3);
    }
    #pragma unroll
    for (int j = 0; j < 4; ++j) {
        gB[j] = Wb + (size_t)(bn + j * 32 + srow) * lda + lcol8;
        dB[j] = (j * 32 + srow) * 64 + (pcol << 3);
    }

    int x0 = ((lg ^ (lr & 7)) << 3);
    int x1 = (((4 + lg) ^ (lr & 7)) << 3);
    int rA[4], rB[2];
    #pragma unroll
    for (int m = 0; m < 4; ++m) rA[m] = (m * 16 + lr) * 64;
    #pragma unroll
    for (int n = 0; n < 2; ++n) rB[n] = (w * 32 + n * 16 + lr) * 64;

    const int nk = K >> 6;          // even for all our shapes (6, 12 or 24)
    STAGE64(0);
    __syncthreads();
    for (int t = 0; t < nk; t += 2) {
        STAGE64(1);
        COMPUTE64(0);
        __syncthreads();
        if (t + 2 < nk) STAGE64(0);
        COMPUTE64(1);
        __syncthreads();
    }

    int r0 = lg * 4;
    #pragma unroll
    for (int m = 0; m < 4; ++m) {
        #pragma unroll
        for (int n = 0; n < 2; ++n) {
            #pragma unroll
            for (int j = 0; j < 4; ++j) {
                int gm = bm + m * 16 + r0 + j;
                int gn = bn + w * 32 + n * 16 + lr;
                float v = acc[m][n][j];
                if (EPI == 1) v = 0.5f * v * (1.0f + erff(v * 0.70710678118654752f));
                if (EPI == 2) v += res[(size_t)gm * N + gn];
                store_val(Cb + (size_t)gm * N + gn, v);
            }
        }
    }
}

// ---------------- MFMA flash attention: one wave per 16-row q-tile.
// V staged per-wave into LDS via global_load_lds (linear dest, XOR-swizzled
// source col ^(issue*16), read back ^(lg*16) -- rule-21 involution), issued
// BEFORE QK^T so the fetch hides under QK^T + softmax (R12-verified variant).
__global__ __launch_bounds__(256)
void attn_mfma_kernel(const ushort* __restrict__ qkv, ushort* __restrict__ o)
{
    int w = threadIdx.x >> 6, l = threadIdx.x & 63;
    int qt = blockIdx.x * 4 + w;
    int h = blockIdx.y, b = blockIdx.z;
    int q0 = qt * 16;
    int lr = l & 15, lg = l >> 4;

    const size_t rs = 3 * D_EMB;    // 2304
    const ushort* qbase = qkv + ((size_t)(b * NTOK)) * rs + h * HDIM;
    const ushort* kbase = qbase + D_EMB;
    const ushort* vbase = qbase + 2 * D_EMB;

    bf16x8 qf[2];
    qf[0] = *(const bf16x8*)(qbase + (size_t)(q0 + lr) * rs + lg * 8);
    qf[1] = *(const bf16x8*)(qbase + (size_t)(q0 + lr) * rs + 32 + lg * 8);

    f32x4 oacc[4] = {};
    float m_j[4], l_j[4];
    #pragma unroll
    for (int j = 0; j < 4; ++j) { m_j[j] = -1e30f; l_j[j] = 0.f; }

    __shared__ ushort V_lds[4][32 * 64];   // 16KB, per-wave slab
    __shared__ ushort P_lds[4][16][40];

    int ntiles = q0 / 32 + 1;
    for (int mt = 0; mt < ntiles; ++mt) {
        int m0 = mt * 32;
        // ---- stage V tile (issued first; flies under QK^T + softmax)
        #pragma unroll
        for (int is = 0; is < 4; ++is) {
            int row = is * 8 + (l >> 3);
            int colel = ((l & 7) * 8) ^ (is * 16);   // inverse-swizzled source
            const ushort* sv = vbase + (size_t)(m0 + row) * rs + colel;
            __builtin_amdgcn_global_load_lds(
                (const __attribute__((address_space(1))) unsigned int*)sv,
                (__attribute__((address_space(3))) unsigned int*)&V_lds[w][is * 512 + l * 8],
                16, 0, 0);
        }
        // ---- S = Q K^T
        f32x4 s[2] = {};
        #pragma unroll
        for (int kb = 0; kb < 2; ++kb) {
            const ushort* kr = kbase + (size_t)(m0 + kb * 16 + lr) * rs;
            bf16x8 k0 = *(const bf16x8*)(kr + lg * 8);
            bf16x8 k1 = *(const bf16x8*)(kr + 32 + lg * 8);
            s[kb] = __builtin_amdgcn_mfma_f32_16x16x32_bf16(qf[0], k0, s[kb], 0, 0, 0);
            s[kb] = __builtin_amdgcn_mfma_f32_16x16x32_bf16(qf[1], k1, s[kb], 0, 0, 0);
        }
        bool partial = (m0 + 31 > q0);
        float p[2][4], mx[4];
        #pragma unroll
        for (int j = 0; j < 4; ++j) {
            int qr = q0 + lg * 4 + j;
            float s0 = s[0][j] * 0.125f;
            float s1 = s[1][j] * 0.125f;
            if (partial) {
                if (m0 + lr > qr)      s0 = -1e30f;
                if (m0 + 16 + lr > qr) s1 = -1e30f;
            }
            p[0][j] = s0; p[1][j] = s1;
            float mm = fmaxf(s0, s1);
            mm = fmaxf(mm, __shfl_xor(mm, 1));
            mm = fmaxf(mm, __shfl_xor(mm, 2));
            mm = fmaxf(mm, __shfl_xor(mm, 4));
            mm = fmaxf(mm, __shfl_xor(mm, 8));
            mx[j] = mm;
        }
        #pragma unroll
        for (int j = 0; j < 4; ++j) {
            float mnew = fmaxf(m_j[j], mx[j]);
            float scale = __expf(m_j[j] - mnew);
            float p0 = __expf(p[0][j] - mnew);
            float p1 = __expf(p[1][j] - mnew);
            p[0][j] = p0; p[1][j] = p1;
            float rsum = p0 + p1;
            rsum += __shfl_xor(rsum, 1);
            rsum += __shfl_xor(rsum, 2);
            rsum += __shfl_xor(rsum, 4);
            rsum += __shfl_xor(rsum, 8);
            l_j[j] = l_j[j] * scale + rsum;
            m_j[j] = mnew;
            #pragma unroll
            for (int i = 0; i < 4; ++i) oacc[i][j] *= scale;
        }
        // ---- P relayout via per-wave LDS
        #pragma unroll
        for (int kb = 0; kb < 2; ++kb)
            #pragma unroll
            for (int j = 0; j < 4; ++j)
                P_lds[w][lg * 4 + j][kb * 16 + lr] = f2bf(p[kb][j]);
        asm volatile("s_waitcnt lgkmcnt(0)" ::: "memory");
        bf16x8 pa = *(const bf16x8*)(&P_lds[w][lr][lg * 8]);
        // ---- V landed? (had QK^T + softmax to fly)
        asm volatile("s_waitcnt vmcnt(0)" ::: "memory");
        // ---- PV from LDS (swizzled read)
        #pragma unroll
        for (int i = 0; i < 4; ++i) {
            bf16x8 vf;
            #pragma unroll
            for (int j = 0; j < 8; ++j)
                vf[j] = (short)V_lds[w][(lg * 8 + j) * 64 + ((i * 16 + lr) ^ (lg * 16))];
            oacc[i] = __builtin_amdgcn_mfma_f32_16x16x32_bf16(pa, vf, oacc[i], 0, 0, 0);
        }
    }
    #pragma unroll
    for (int i = 0; i < 4; ++i) {
        #pragma unroll
        for (int j = 0; j < 4; ++j) {
            int qr = q0 + lg * 4 + j;
            int d  = i * 16 + lr;
            float v = oacc[i][j] / l_j[j];
            o[((size_t)(b * NTOK + qr)) * D_EMB + h * HDIM + d] = f2bf(v);
        }
    }
}

// ---------------- mean over tokens
__global__ void mean_kernel(const float* __restrict__ x, float* __restrict__ enc)
{
    int b = blockIdx.x; int d = threadIdx.x;    // 768 threads
    float s = 0.f;
    for (int n = 0; n < NTOK; ++n) s += x[((size_t)(b * NTOK + n)) * D_EMB + d];
    enc[b * D_EMB + d] = s * (1.0f / NTOK);
}

// ---------------- heads
__global__ void head1_kernel(const float* __restrict__ enc, const float* __restrict__ w,
                             const float* __restrict__ bias, float* __restrict__ r)
{
    int b = blockIdx.x; int j = threadIdx.x;    // 384 threads
    float acc = bias[j];
    const float* e = enc + b * D_EMB;
    const float* wr = w + (size_t)j * D_EMB;
    for (int k = 0; k < D_EMB; ++k) acc += e[k] * wr[k];
    r[b * 384 + j] = fmaxf(acc, 0.f);
}

__global__ void head2_kernel(const float* __restrict__ r, const float* __restrict__ w,
                             const float* __restrict__ bias, float* __restrict__ out)
{
    int idx = threadIdx.x;
    if (idx >= 16) return;
    int b = idx >> 1, j = idx & 1;
    float acc = bias[j];
    for (int k = 0; k < 384; ++k) acc += r[b * 384 + k] * w[j * 384 + k];
    out[b * 2 + j] = acc;
}

extern "C" void kernel_launch(void* const* d_in, const int* in_sizes, int n_in,
                              void* d_out, int out_size, void* d_ws, size_t ws_size,
                              hipStream_t stream)
{
    const float* x     = (const float*)d_in[0];
    const float* pp_w  = (const float*)d_in[1];
    const float* pp_b  = (const float*)d_in[2];
    const float* pe    = (const float*)d_in[3];
    const float* ln1_g = (const float*)d_in[4];
    const float* ln1_b = (const float*)d_in[5];
    const float* qkv_w = (const float*)d_in[6];
    const float* out_w = (const float*)d_in[7];
    const float* ln2_g = (const float*)d_in[8];
    const float* ln2_b = (const float*)d_in[9];
    const float* fc1_w = (const float*)d_in[10];
    const float* fc2_w = (const float*)d_in[11];
    const float* lnf_g = (const float*)d_in[12];
    const float* lnf_b = (const float*)d_in[13];
    const float* h1_w  = (const float*)d_in[14];
    const float* h1_b  = (const float*)d_in[15];
    const float* h2_w  = (const float*)d_in[16];
    const float* h2_b  = (const float*)d_in[17];
    float* out = (float*)d_out;

    const int nq = 3 * D_EMB * D_EMB, no = D_EMB * D_EMB, nf = DFF * D_EMB;
    const size_t per_layer_w = ((size_t)nq + no + 2 * nf) * 2;   // bytes

    char* p = (char*)d_ws;
    float*  z      = (float*)p;  p += (size_t)MTOK * D_EMB * 4;
    ushort* big_bf = (ushort*)p; p += (size_t)MTOK * DFF * 2;
    ushort* h_bf   = (ushort*)p; p += (size_t)MTOK * D_EMB * 2;
    float*  pbuf   = (float*)p;  p += (size_t)2 * MTOK * D_EMB * 4;
    float*  enc    = (float*)p;  p += BATCH * D_EMB * 4;
    float*  r1     = (float*)p;  p += BATCH * 384 * 4;
    size_t base_used = (size_t)(p - (char*)d_ws);
    bool full = (ws_size >= base_used + NLAYER * per_layer_w);
    int nlw = full ? NLAYER : 1;
    ushort* wq_bf  = (ushort*)p; p += (size_t)nlw * nq * 2;
    ushort* wo_bf  = (ushort*)p; p += (size_t)nlw * no * 2;
    ushort* wf1_bf = (ushort*)p; p += (size_t)nlw * nf * 2;
    ushort* wf2_bf = (ushort*)p; p += (size_t)nlw * nf * 2;
    float*  lnf_out = (float*)big_bf;   // reuse

    patch_embed_kernel<<<MTOK, 256, 0, stream>>>(x, pp_w, pp_b, pe, z);

    if (full) {
        // convert ALL layers' weights in one grid-stride launch (4 elems/thr)
        long long tq = (long long)NLAYER * nq / 4, to = (long long)NLAYER * no / 4;
        long long tf = (long long)NLAYER * nf / 4;
        f2bf4_kernel<<<2048, 256, 0, stream>>>(
            qkv_w, wq_bf, (int)tq, out_w, wo_bf, (int)to,
            fc1_w, wf1_bf, (int)tf, fc2_w, wf2_bf, (int)tf);
    }

    // ln1 of layer 0 (later layers get it fused into reduce_ln)
    ln_kernel<ushort><<<MTOK, 256, 0, stream>>>(z, ln1_g, ln1_b, h_bf);

    for (int i = 0; i < NLAYER; ++i) {
        const ushort* wq  = wq_bf  + (full ? (size_t)i * nq : 0);
        const ushort* wo  = wo_bf  + (full ? (size_t)i * no : 0);
        const ushort* wf1 = wf1_bf + (full ? (size_t)i * nf : 0);
        const ushort* wf2 = wf2_bf + (full ? (size_t)i * nf : 0);
        if (!full) {
            f2bf4_kernel<<<2048, 256, 0, stream>>>(
                qkv_w + (size_t)i * nq, wq_bf,  nq / 4,
                out_w + (size_t)i * no, wo_bf,  no / 4,
                fc1_w + (size_t)i * nf, wf1_bf, nf / 4,
                fc2_w + (size_t)i * nf, wf2_bf, nf / 4);
        }

        dim3 gq((3 * D_EMB) / 128, MTOK / 64);
        mfma_gemm<0, ushort, false><<<gq, 256, 0, stream>>>(h_bf, wq, big_bf, nullptr,
                                                            3 * D_EMB, D_EMB, D_EMB);

        dim3 ga(NTOK / 64, NHEAD, BATCH);
        attn_mfma_kernel<<<ga, 256, 0, stream>>>(big_bf, h_bf);

        // proj: split-K x2 -> pbuf partials (grid 384 -> 768 blocks)
        dim3 gp(D_EMB / 128, MTOK / 64, 2);
        mfma_gemm<0, float, true><<<gp, 256, 0, stream>>>(h_bf, wo, pbuf, nullptr,
                                                          D_EMB, D_EMB / 2, D_EMB);
        // fused: z += p0+p1, then ln2 -> h_bf
        reduce_ln_kernel<ushort><<<MTOK, 256, 0, stream>>>(
            pbuf, z, ln2_g + i * D_EMB, ln2_b + i * D_EMB, h_bf);

        dim3 g1(DFF / 128, MTOK / 64);
        mfma_gemm<1, ushort, false><<<g1, 256, 0, stream>>>(h_bf, wf1, big_bf, nullptr,
                                                            DFF, D_EMB, D_EMB);

        dim3 g2(D_EMB / 128, MTOK / 64, 2);
        mfma_gemm<0, float, true><<<g2, 256, 0, stream>>>(big_bf, wf2, pbuf, nullptr,
                                                          D_EMB, DFF / 2, DFF);

        if (i < NLAYER - 1) {
            reduce_ln_kernel<ushort><<<MTOK, 256, 0, stream>>>(
                pbuf, z, ln1_g + (i + 1) * D_EMB, ln1_b + (i + 1) * D_EMB, h_bf);
        } else {
            reduce_ln_kernel<float><<<MTOK, 256, 0, stream>>>(
                pbuf, z, lnf_g, lnf_b, lnf_out);
        }
    }

    mean_kernel<<<BATCH, D_EMB, 0, stream>>>(lnf_out, enc);
    head1_kernel<<<BATCH, 384, 0, stream>>>(enc, h1_w, h1_b, r1);
    head2_kernel<<<1, 64, 0, stream>>>(r1, h2_w, h2_b, out);
}

// Round 17
// 1074.135 us; speedup vs baseline: 1.0305x; 1.0305x over previous
//
#include <hip/hip_runtime.h>
#include <hip/hip_bf16.h>
#include <math.h>

#define D_EMB 768
#define NPATCH 16
#define NTOK 512
#define NHEAD 12
#define HDIM 64
#define NLAYER 6
#define DFF 3072
#define BATCH 8
#define MTOK (BATCH * NTOK)   // 4096 rows

typedef __attribute__((ext_vector_type(8))) short bf16x8;
typedef __attribute__((ext_vector_type(4))) float f32x4;

__device__ __forceinline__ float bf2f(ushort s) {
    unsigned u = ((unsigned)s) << 16;
    return __builtin_bit_cast(float, u);
}
__device__ __forceinline__ ushort f2bf(float f) {
    unsigned u = __builtin_bit_cast(unsigned, f);
    unsigned r = (u + 0x7FFFu + ((u >> 16) & 1u)) >> 16;   // RNE
    return (ushort)r;
}

// ---------------- fp32 -> bf16 convert, 4 segments, 4 elems/thread, one-shot
// grid (R13 measured-fastest form: 59-62us vs 8-elem 63-67, grid-stride 64-71).
// counts n0..n3 are in UNITS OF 4 ELEMENTS.
__global__ __launch_bounds__(256)
void f2bf4_kernel(const float* __restrict__ s0, ushort* __restrict__ d0, int n0,
                  const float* __restrict__ s1, ushort* __restrict__ d1, int n1,
                  const float* __restrict__ s2, ushort* __restrict__ d2, int n2,
                  const float* __restrict__ s3, ushort* __restrict__ d3, int n3)
{
    int i = blockIdx.x * 256 + threadIdx.x;
    const float* s; ushort* d; int off;
    if (i < n0)                { s = s0; d = d0; off = i; }
    else if (i < n0 + n1)      { s = s1; d = d1; off = i - n0; }
    else if (i < n0 + n1 + n2) { s = s2; d = d2; off = i - n0 - n1; }
    else if (i < n0 + n1 + n2 + n3) { s = s3; d = d3; off = i - n0 - n1 - n2; }
    else return;
    float4 v = *(const float4*)(s + (size_t)off * 4);
    ushort4 o;
    o.x = f2bf(v.x); o.y = f2bf(v.y); o.z = f2bf(v.z); o.w = f2bf(v.w);
    *(ushort4*)(d + (size_t)off * 4) = o;
}

// ---------------- patch embed
__global__ __launch_bounds__(256)
void patch_embed_kernel(const float* __restrict__ x, const float* __restrict__ pw,
                        const float* __restrict__ pb, const float* __restrict__ pe,
                        float* __restrict__ z)
{
    int bn = blockIdx.x;            // 0..4095
    int b = bn >> 9, n = bn & 511;
    __shared__ float xs[NPATCH];
    int t = threadIdx.x;
    if (t < NPATCH) xs[t] = x[(size_t)b * 8192 + n * NPATCH + t];
    __syncthreads();
    for (int d = t; d < D_EMB; d += 256) {
        float acc = pb[d] + pe[(size_t)n * D_EMB + d];
        const float* w = pw + (size_t)d * NPATCH;
        #pragma unroll
        for (int p = 0; p < NPATCH; ++p) acc += xs[p] * w[p];
        z[(size_t)bn * D_EMB + d] = acc;
    }
}

// ---------------- block reduce (256 threads = 4 waves)
__device__ __forceinline__ float block_reduce_sum_256(float v)
{
    __shared__ float lds[4];
    #pragma unroll
    for (int o = 32; o > 0; o >>= 1) v += __shfl_xor(v, o);
    int lane = threadIdx.x & 63, wid = threadIdx.x >> 6;
    __syncthreads();
    if (lane == 0) lds[wid] = v;
    __syncthreads();
    return lds[0] + lds[1] + lds[2] + lds[3];
}

__device__ __forceinline__ void store_val(float* p, float v)  { *p = v; }
__device__ __forceinline__ void store_val(ushort* p, float v) { *p = f2bf(v); }

// ---------------- layernorm over D=768, one block (256 thr) per row
template<typename OT>
__global__ __launch_bounds__(256)
void ln_kernel(const float* __restrict__ x, const float* __restrict__ g,
               const float* __restrict__ bta, OT* __restrict__ y)
{
    int row = blockIdx.x;
    const float* xr = x + (size_t)row * D_EMB;
    int t = threadIdx.x;
    float vals[3];
    float s = 0.f;
    #pragma unroll
    for (int i = 0; i < 3; ++i) { vals[i] = xr[t + i * 256]; s += vals[i]; }
    float mean = block_reduce_sum_256(s) * (1.0f / D_EMB);
    float ss = 0.f;
    #pragma unroll
    for (int i = 0; i < 3; ++i) { float d = vals[i] - mean; ss += d * d; }
    float var = block_reduce_sum_256(ss) * (1.0f / D_EMB);
    float rstd = rsqrtf(var + 1e-5f);
    #pragma unroll
    for (int i = 0; i < 3; ++i) {
        int d = t + i * 256;
        store_val(y + (size_t)row * D_EMB + d, (vals[i] - mean) * rstd * g[d] + bta[d]);
    }
}

// ---------------- fused split-K reduce + residual + layernorm
template<typename OT>
__global__ __launch_bounds__(256)
void reduce_ln_kernel(const float* __restrict__ pbuf, float* __restrict__ z,
                      const float* __restrict__ g, const float* __restrict__ bta,
                      OT* __restrict__ y)
{
    int row = blockIdx.x;
    int t = threadIdx.x;
    const float* p0 = pbuf + (size_t)row * D_EMB;
    const float* p1 = pbuf + (size_t)MTOK * D_EMB + (size_t)row * D_EMB;
    float* zr = z + (size_t)row * D_EMB;
    float vals[3];
    float s = 0.f;
    #pragma unroll
    for (int i = 0; i < 3; ++i) {
        int d = t + i * 256;
        float v = zr[d] + p0[d] + p1[d];
        vals[i] = v;
        zr[d] = v;
        s += v;
    }
    float mean = block_reduce_sum_256(s) * (1.0f / D_EMB);
    float ss = 0.f;
    #pragma unroll
    for (int i = 0; i < 3; ++i) { float d = vals[i] - mean; ss += d * d; }
    float var = block_reduce_sum_256(ss) * (1.0f / D_EMB);
    float rstd = rsqrtf(var + 1e-5f);
    #pragma unroll
    for (int i = 0; i < 3; ++i) {
        int d = t + i * 256;
        store_val(y + (size_t)row * D_EMB + d, (vals[i] - mean) * rstd * g[d] + bta[d]);
    }
}

// ---------------- bf16 MFMA GEMM (R15 form: strength-reduced addresses)
// 64x128 tile, BK=64, 4 waves, global_load_lds w=16, rule-21 XOR swizzle,
// R6 M-slice XCD map, 2-buffer issue-early prefetch, ping-pong unroll.
// EPI: 0 = none, 1 = exact gelu, 2 = add residual(fp32)
// SPLITK: grid.z = K-chunks; A/W advance by bz*K, C by bz*(gy*64)*N partials.
#define STAGE64(buf)                                                               \
    {                                                                              \
        _Pragma("unroll")                                                          \
        for (int j = 0; j < 2; ++j) {                                              \
            __builtin_amdgcn_global_load_lds(                                      \
                (const __attribute__((address_space(1))) unsigned int*)gA[j],      \
                (__attribute__((address_space(3))) unsigned int*)&As[buf][dA[j]],  \
                16, 0, 0);                                                         \
            gA[j] += 64;                                                           \
        }                                                                          \
        _Pragma("unroll")                                                          \
        for (int j = 0; j < 4; ++j) {                                              \
            __builtin_amdgcn_global_load_lds(                                      \
                (const __attribute__((address_space(1))) unsigned int*)gB[j],      \
                (__attribute__((address_space(3))) unsigned int*)&Bs[buf][dB[j]],  \
                16, 0, 0);                                                         \
            gB[j] += 64;                                                           \
        }                                                                          \
    }

#define COMPUTE64(buf)                                                             \
    {                                                                              \
        bf16x8 a0[4], a1[4], b0[2], b1[2];                                         \
        _Pragma("unroll")                                                          \
        for (int m = 0; m < 4; ++m) {                                              \
            a0[m] = *(const bf16x8*)(&As[buf][rA[m] + x0]);                        \
            a1[m] = *(const bf16x8*)(&As[buf][rA[m] + x1]);                        \
        }                                                                          \
        _Pragma("unroll")                                                          \
        for (int n = 0; n < 2; ++n) {                                              \
            b0[n] = *(const bf16x8*)(&Bs[buf][rB[n] + x0]);                        \
            b1[n] = *(const bf16x8*)(&Bs[buf][rB[n] + x1]);                        \
        }                                                                          \
        _Pragma("unroll")                                                          \
        for (int m = 0; m < 4; ++m)                                                \
            _Pragma("unroll")                                                      \
            for (int n = 0; n < 2; ++n)                                            \
                acc[m][n] = __builtin_amdgcn_mfma_f32_16x16x32_bf16(a0[m], b0[n], acc[m][n], 0, 0, 0); \
        _Pragma("unroll")                                                          \
        for (int m = 0; m < 4; ++m)                                                \
            _Pragma("unroll")                                                      \
            for (int n = 0; n < 2; ++n)                                            \
                acc[m][n] = __builtin_amdgcn_mfma_f32_16x16x32_bf16(a1[m], b1[n], acc[m][n], 0, 0, 0); \
    }

template<int EPI, typename OT, bool SPLITK>
__global__ __launch_bounds__(256)
void mfma_gemm(const ushort* __restrict__ A, const ushort* __restrict__ W,
               OT* __restrict__ C, const float* __restrict__ res,
               int N, int K, int lda)
{
    __shared__ ushort As[2][64 * 64];
    __shared__ ushort Bs[2][128 * 64];

    int gx = gridDim.x, gy = gridDim.y;
    int bx = blockIdx.x, by = blockIdx.y;
    int bz = SPLITK ? blockIdx.z : 0;
    if ((gy & 7) == 0) {
        int flat = bx + gx * (by + gy * bz);
        int xcd = flat & 7, j = flat >> 3;
        int ry = gy >> 3;
        by = xcd * ry + (j % ry);
        int rem = j / ry;
        bx = rem % gx;
        bz = rem / gx;
    }
    int bm = by * 64, bn = bx * 128;

    const ushort* Ab = A + (size_t)bz * K;
    const ushort* Wb = W + (size_t)bz * K;
    OT* Cb = C + (SPLITK ? (size_t)bz * ((size_t)gy * 64) * N : 0);

    int tid = threadIdx.x;
    int w = tid >> 6, l = tid & 63;
    int lr = l & 15, lg = l >> 4;
    f32x4 acc[4][2] = {};

    int srow = w * 8 + (l >> 3);
    int pcol = l & 7;
    int lcol8 = (pcol ^ (srow & 7)) << 3;

    const ushort* gA[2]; const ushort* gB[4];
    int dA[2], dB[4];
    #pragma unroll
    for (int j = 0; j < 2; ++j) {
        gA[j] = Ab + (size_t)(bm + j * 32 + srow) * lda + lcol8;
        dA[j] = (j * 32 + srow) * 64 + (pcol << 3);
    }
    #pragma unroll
    for (int j = 0; j < 4; ++j) {
        gB[j] = Wb + (size_t)(bn + j * 32 + srow) * lda + lcol8;
        dB[j] = (j * 32 + srow) * 64 + (pcol << 3);
    }

    int x0 = ((lg ^ (lr & 7)) << 3);
    int x1 = (((4 + lg) ^ (lr & 7)) << 3);
    int rA[4], rB[2];
    #pragma unroll
    for (int m = 0; m < 4; ++m) rA[m] = (m * 16 + lr) * 64;
    #pragma unroll
    for (int n = 0; n < 2; ++n) rB[n] = (w * 32 + n * 16 + lr) * 64;

    const int nk = K >> 6;          // even for all our shapes (12 or 24)
    STAGE64(0);
    __syncthreads();
    for (int t = 0; t < nk; t += 2) {
        STAGE64(1);                 // prefetch tile t+1 (flies during compute)
        COMPUTE64(0);               // compute tile t
        __syncthreads();
        if (t + 2 < nk) STAGE64(0); // prefetch tile t+2
        COMPUTE64(1);               // compute tile t+1
        __syncthreads();
    }

    int r0 = lg * 4;
    #pragma unroll
    for (int m = 0; m < 4; ++m) {
        #pragma unroll
        for (int n = 0; n < 2; ++n) {
            #pragma unroll
            for (int j = 0; j < 4; ++j) {
                int gm = bm + m * 16 + r0 + j;
                int gn = bn + w * 32 + n * 16 + lr;
                float v = acc[m][n][j];
                if (EPI == 1) v = 0.5f * v * (1.0f + erff(v * 0.70710678118654752f));
                if (EPI == 2) v += res[(size_t)gm * N + gn];
                store_val(Cb + (size_t)gm * N + gn, v);
            }
        }
    }
}

// ---------------- MFMA flash attention: one wave per 16-row q-tile (R10 form)
__global__ __launch_bounds__(256)
void attn_mfma_kernel(const ushort* __restrict__ qkv, ushort* __restrict__ o)
{
    int w = threadIdx.x >> 6, l = threadIdx.x & 63;
    int qt = blockIdx.x * 4 + w;
    int h = blockIdx.y, b = blockIdx.z;
    int q0 = qt * 16;
    int lr = l & 15, lg = l >> 4;

    const size_t rs = 3 * D_EMB;    // 2304
    const ushort* qbase = qkv + ((size_t)(b * NTOK)) * rs + h * HDIM;
    const ushort* kbase = qbase + D_EMB;
    const ushort* vbase = qbase + 2 * D_EMB;

    bf16x8 qf[2];
    qf[0] = *(const bf16x8*)(qbase + (size_t)(q0 + lr) * rs + lg * 8);
    qf[1] = *(const bf16x8*)(qbase + (size_t)(q0 + lr) * rs + 32 + lg * 8);

    f32x4 oacc[4] = {};
    float m_j[4], l_j[4];
    #pragma unroll
    for (int j = 0; j < 4; ++j) { m_j[j] = -1e30f; l_j[j] = 0.f; }

    __shared__ ushort P_lds[4][16][40];

    int ntiles = q0 / 32 + 1;
    for (int mt = 0; mt < ntiles; ++mt) {
        int m0 = mt * 32;
        f32x4 s[2] = {};
        #pragma unroll
        for (int kb = 0; kb < 2; ++kb) {
            const ushort* kr = kbase + (size_t)(m0 + kb * 16 + lr) * rs;
            bf16x8 k0 = *(const bf16x8*)(kr + lg * 8);
            bf16x8 k1 = *(const bf16x8*)(kr + 32 + lg * 8);
            s[kb] = __builtin_amdgcn_mfma_f32_16x16x32_bf16(qf[0], k0, s[kb], 0, 0, 0);
            s[kb] = __builtin_amdgcn_mfma_f32_16x16x32_bf16(qf[1], k1, s[kb], 0, 0, 0);
        }
        bool partial = (m0 + 31 > q0);
        float p[2][4], mx[4];
        #pragma unroll
        for (int j = 0; j < 4; ++j) {
            int qr = q0 + lg * 4 + j;
            float s0 = s[0][j] * 0.125f;
            float s1 = s[1][j] * 0.125f;
            if (partial) {
                if (m0 + lr > qr)      s0 = -1e30f;
                if (m0 + 16 + lr > qr) s1 = -1e30f;
            }
            p[0][j] = s0; p[1][j] = s1;
            float mm = fmaxf(s0, s1);
            mm = fmaxf(mm, __shfl_xor(mm, 1));
            mm = fmaxf(mm, __shfl_xor(mm, 2));
            mm = fmaxf(mm, __shfl_xor(mm, 4));
            mm = fmaxf(mm, __shfl_xor(mm, 8));
            mx[j] = mm;
        }
        #pragma unroll
        for (int j = 0; j < 4; ++j) {
            float mnew = fmaxf(m_j[j], mx[j]);
            float scale = __expf(m_j[j] - mnew);
            float p0 = __expf(p[0][j] - mnew);
            float p1 = __expf(p[1][j] - mnew);
            p[0][j] = p0; p[1][j] = p1;
            float rsum = p0 + p1;
            rsum += __shfl_xor(rsum, 1);
            rsum += __shfl_xor(rsum, 2);
            rsum += __shfl_xor(rsum, 4);
            rsum += __shfl_xor(rsum, 8);
            l_j[j] = l_j[j] * scale + rsum;
            m_j[j] = mnew;
            #pragma unroll
            for (int i = 0; i < 4; ++i) oacc[i][j] *= scale;
        }
        #pragma unroll
        for (int kb = 0; kb < 2; ++kb)
            #pragma unroll
            for (int j = 0; j < 4; ++j)
                P_lds[w][lg * 4 + j][kb * 16 + lr] = f2bf(p[kb][j]);
        asm volatile("s_waitcnt lgkmcnt(0)" ::: "memory");
        bf16x8 pa = *(const bf16x8*)(&P_lds[w][lr][lg * 8]);
        #pragma unroll
        for (int i = 0; i < 4; ++i) {
            bf16x8 vf;
            const ushort* vp = vbase + (size_t)(m0 + lg * 8) * rs + i * 16 + lr;
            #pragma unroll
            for (int j = 0; j < 8; ++j) vf[j] = (short)vp[(size_t)j * rs];
            oacc[i] = __builtin_amdgcn_mfma_f32_16x16x32_bf16(pa, vf, oacc[i], 0, 0, 0);
        }
    }
    #pragma unroll
    for (int i = 0; i < 4; ++i) {
        #pragma unroll
        for (int j = 0; j < 4; ++j) {
            int qr = q0 + lg * 4 + j;
            int d  = i * 16 + lr;
            float v = oacc[i][j] / l_j[j];
            o[((size_t)(b * NTOK + qr)) * D_EMB + h * HDIM + d] = f2bf(v);
        }
    }
}

// ---------------- mean over tokens
__global__ void mean_kernel(const float* __restrict__ x, float* __restrict__ enc)
{
    int b = blockIdx.x; int d = threadIdx.x;    // 768 threads
    float s = 0.f;
    for (int n = 0; n < NTOK; ++n) s += x[((size_t)(b * NTOK + n)) * D_EMB + d];
    enc[b * D_EMB + d] = s * (1.0f / NTOK);
}

// ---------------- heads
__global__ void head1_kernel(const float* __restrict__ enc, const float* __restrict__ w,
                             const float* __restrict__ bias, float* __restrict__ r)
{
    int b = blockIdx.x; int j = threadIdx.x;    // 384 threads
    float acc = bias[j];
    const float* e = enc + b * D_EMB;
    const float* wr = w + (size_t)j * D_EMB;
    for (int k = 0; k < D_EMB; ++k) acc += e[k] * wr[k];
    r[b * 384 + j] = fmaxf(acc, 0.f);
}

__global__ void head2_kernel(const float* __restrict__ r, const float* __restrict__ w,
                             const float* __restrict__ bias, float* __restrict__ out)
{
    int idx = threadIdx.x;
    if (idx >= 16) return;
    int b = idx >> 1, j = idx & 1;
    float acc = bias[j];
    for (int k = 0; k < 384; ++k) acc += r[b * 384 + k] * w[j * 384 + k];
    out[b * 2 + j] = acc;
}

extern "C" void kernel_launch(void* const* d_in, const int* in_sizes, int n_in,
                              void* d_out, int out_size, void* d_ws, size_t ws_size,
                              hipStream_t stream)
{
    const float* x     = (const float*)d_in[0];
    const float* pp_w  = (const float*)d_in[1];
    const float* pp_b  = (const float*)d_in[2];
    const float* pe    = (const float*)d_in[3];
    const float* ln1_g = (const float*)d_in[4];
    const float* ln1_b = (const float*)d_in[5];
    const float* qkv_w = (const float*)d_in[6];
    const float* out_w = (const float*)d_in[7];
    const float* ln2_g = (const float*)d_in[8];
    const float* ln2_b = (const float*)d_in[9];
    const float* fc1_w = (const float*)d_in[10];
    const float* fc2_w = (const float*)d_in[11];
    const float* lnf_g = (const float*)d_in[12];
    const float* lnf_b = (const float*)d_in[13];
    const float* h1_w  = (const float*)d_in[14];
    const float* h1_b  = (const float*)d_in[15];
    const float* h2_w  = (const float*)d_in[16];
    const float* h2_b  = (const float*)d_in[17];
    float* out = (float*)d_out;

    const int nq = 3 * D_EMB * D_EMB, no = D_EMB * D_EMB, nf = DFF * D_EMB;
    const size_t per_layer_w = ((size_t)nq + no + 2 * nf) * 2;   // bytes

    char* p = (char*)d_ws;
    float*  z      = (float*)p;  p += (size_t)MTOK * D_EMB * 4;
    ushort* big_bf = (ushort*)p; p += (size_t)MTOK * DFF * 2;
    ushort* h_bf   = (ushort*)p; p += (size_t)MTOK * D_EMB * 2;
    float*  pbuf   = (float*)p;  p += (size_t)2 * MTOK * D_EMB * 4;
    float*  enc    = (float*)p;  p += BATCH * D_EMB * 4;
    float*  r1     = (float*)p;  p += BATCH * 384 * 4;
    size_t base_used = (size_t)(p - (char*)d_ws);
    bool full = (ws_size >= base_used + NLAYER * per_layer_w);
    int nlw = full ? NLAYER : 1;
    ushort* wq_bf  = (ushort*)p; p += (size_t)nlw * nq * 2;
    ushort* wo_bf  = (ushort*)p; p += (size_t)nlw * no * 2;
    ushort* wf1_bf = (ushort*)p; p += (size_t)nlw * nf * 2;
    ushort* wf2_bf = (ushort*)p; p += (size_t)nlw * nf * 2;
    float*  lnf_out = (float*)big_bf;   // reuse

    patch_embed_kernel<<<MTOK, 256, 0, stream>>>(x, pp_w, pp_b, pe, z);

    if (full) {
        // convert ALL layers' weights in one launch (4 elems/thread, one-shot)
        long long tq = (long long)NLAYER * nq / 4, to = (long long)NLAYER * no / 4;
        long long tf = (long long)NLAYER * nf / 4;
        long long tot = tq + to + 2 * tf;
        f2bf4_kernel<<<(int)((tot + 255) / 256), 256, 0, stream>>>(
            qkv_w, wq_bf, (int)tq, out_w, wo_bf, (int)to,
            fc1_w, wf1_bf, (int)tf, fc2_w, wf2_bf, (int)tf);
    }

    // ln1 of layer 0 (later layers get it fused into reduce_ln)
    ln_kernel<ushort><<<MTOK, 256, 0, stream>>>(z, ln1_g, ln1_b, h_bf);

    const int cvt_blocks = (nq / 4 + no / 4 + 2 * (nf / 4) + 255) / 256;

    for (int i = 0; i < NLAYER; ++i) {
        const ushort* wq  = wq_bf  + (full ? (size_t)i * nq : 0);
        const ushort* wo  = wo_bf  + (full ? (size_t)i * no : 0);
        const ushort* wf1 = wf1_bf + (full ? (size_t)i * nf : 0);
        const ushort* wf2 = wf2_bf + (full ? (size_t)i * nf : 0);
        if (!full) {
            f2bf4_kernel<<<cvt_blocks, 256, 0, stream>>>(
                qkv_w + (size_t)i * nq, wq_bf,  nq / 4,
                out_w + (size_t)i * no, wo_bf,  no / 4,
                fc1_w + (size_t)i * nf, wf1_bf, nf / 4,
                fc2_w + (size_t)i * nf, wf2_bf, nf / 4);
        }

        dim3 gq((3 * D_EMB) / 128, MTOK / 64);
        mfma_gemm<0, ushort, false><<<gq, 256, 0, stream>>>(h_bf, wq, big_bf, nullptr,
                                                            3 * D_EMB, D_EMB, D_EMB);

        dim3 ga(NTOK / 64, NHEAD, BATCH);
        attn_mfma_kernel<<<ga, 256, 0, stream>>>(big_bf, h_bf);

        dim3 gp(D_EMB / 128, MTOK / 64);
        mfma_gemm<2, float, false><<<gp, 256, 0, stream>>>(h_bf, wo, z, z,
                                                           D_EMB, D_EMB, D_EMB);

        ln_kernel<ushort><<<MTOK, 256, 0, stream>>>(z, ln2_g + i * D_EMB, ln2_b + i * D_EMB, h_bf);

        dim3 g1(DFF / 128, MTOK / 64);
        mfma_gemm<1, ushort, false><<<g1, 256, 0, stream>>>(h_bf, wf1, big_bf, nullptr,
                                                            DFF, D_EMB, D_EMB);

        dim3 g2(D_EMB / 128, MTOK / 64, 2);
        mfma_gemm<0, float, true><<<g2, 256, 0, stream>>>(big_bf, wf2, pbuf, nullptr,
                                                          D_EMB, DFF / 2, DFF);

        if (i < NLAYER - 1) {
            reduce_ln_kernel<ushort><<<MTOK, 256, 0, stream>>>(
                pbuf, z, ln1_g + (i + 1) * D_EMB, ln1_b + (i + 1) * D_EMB, h_bf);
        } else {
            reduce_ln_kernel<float><<<MTOK, 256, 0, stream>>>(
                pbuf, z, lnf_g, lnf_b, lnf_out);
        }
    }

    mean_kernel<<<BATCH, D_EMB, 0, stream>>>(lnf_out, enc);
    head1_kernel<<<BATCH, 384, 0, stream>>>(enc, h1_w, h1_b, r1);
    head2_kernel<<<1, 64, 0, stream>>>(r1, h2_w, h2_b, out);
}

// Round 18
// 1072.427 us; speedup vs baseline: 1.0321x; 1.0016x over previous
//
#include <hip/hip_runtime.h>
#include <hip/hip_bf16.h>
#include <math.h>

#define D_EMB 768
#define NPATCH 16
#define NTOK 512
#define NHEAD 12
#define HDIM 64
#define NLAYER 6
#define DFF 3072
#define BATCH 8
#define MTOK (BATCH * NTOK)   // 4096 rows

typedef __attribute__((ext_vector_type(8))) short bf16x8;
typedef __attribute__((ext_vector_type(4))) float f32x4;

__device__ __forceinline__ float bf2f(ushort s) {
    unsigned u = ((unsigned)s) << 16;
    return __builtin_bit_cast(float, u);
}
__device__ __forceinline__ ushort f2bf(float f) {
    unsigned u = __builtin_bit_cast(unsigned, f);
    unsigned r = (u + 0x7FFFu + ((u >> 16) & 1u)) >> 16;   // RNE
    return (ushort)r;
}

// ---------------- fp32 -> bf16 convert, 4 segments, 4 elems/thread, one-shot
// grid (R13/R17 measured-fastest form). counts in UNITS OF 4 ELEMENTS.
__global__ __launch_bounds__(256)
void f2bf4_kernel(const float* __restrict__ s0, ushort* __restrict__ d0, int n0,
                  const float* __restrict__ s1, ushort* __restrict__ d1, int n1,
                  const float* __restrict__ s2, ushort* __restrict__ d2, int n2,
                  const float* __restrict__ s3, ushort* __restrict__ d3, int n3)
{
    int i = blockIdx.x * 256 + threadIdx.x;
    const float* s; ushort* d; int off;
    if (i < n0)                { s = s0; d = d0; off = i; }
    else if (i < n0 + n1)      { s = s1; d = d1; off = i - n0; }
    else if (i < n0 + n1 + n2) { s = s2; d = d2; off = i - n0 - n1; }
    else if (i < n0 + n1 + n2 + n3) { s = s3; d = d3; off = i - n0 - n1 - n2; }
    else return;
    float4 v = *(const float4*)(s + (size_t)off * 4);
    ushort4 o;
    o.x = f2bf(v.x); o.y = f2bf(v.y); o.z = f2bf(v.z); o.w = f2bf(v.w);
    *(ushort4*)(d + (size_t)off * 4) = o;
}

// ---------------- patch embed
__global__ __launch_bounds__(256)
void patch_embed_kernel(const float* __restrict__ x, const float* __restrict__ pw,
                        const float* __restrict__ pb, const float* __restrict__ pe,
                        float* __restrict__ z)
{
    int bn = blockIdx.x;            // 0..4095
    int b = bn >> 9, n = bn & 511;
    __shared__ float xs[NPATCH];
    int t = threadIdx.x;
    if (t < NPATCH) xs[t] = x[(size_t)b * 8192 + n * NPATCH + t];
    __syncthreads();
    for (int d = t; d < D_EMB; d += 256) {
        float acc = pb[d] + pe[(size_t)n * D_EMB + d];
        const float* w = pw + (size_t)d * NPATCH;
        #pragma unroll
        for (int p = 0; p < NPATCH; ++p) acc += xs[p] * w[p];
        z[(size_t)bn * D_EMB + d] = acc;
    }
}

// ---------------- block reduce (256 threads = 4 waves)
__device__ __forceinline__ float block_reduce_sum_256(float v)
{
    __shared__ float lds[4];
    #pragma unroll
    for (int o = 32; o > 0; o >>= 1) v += __shfl_xor(v, o);
    int lane = threadIdx.x & 63, wid = threadIdx.x >> 6;
    __syncthreads();
    if (lane == 0) lds[wid] = v;
    __syncthreads();
    return lds[0] + lds[1] + lds[2] + lds[3];
}

__device__ __forceinline__ void store_val(float* p, float v)  { *p = v; }
__device__ __forceinline__ void store_val(ushort* p, float v) { *p = f2bf(v); }

// ---------------- layernorm over D=768, one block (256 thr) per row
template<typename OT>
__global__ __launch_bounds__(256)
void ln_kernel(const float* __restrict__ x, const float* __restrict__ g,
               const float* __restrict__ bta, OT* __restrict__ y)
{
    int row = blockIdx.x;
    const float* xr = x + (size_t)row * D_EMB;
    int t = threadIdx.x;
    float vals[3];
    float s = 0.f;
    #pragma unroll
    for (int i = 0; i < 3; ++i) { vals[i] = xr[t + i * 256]; s += vals[i]; }
    float mean = block_reduce_sum_256(s) * (1.0f / D_EMB);
    float ss = 0.f;
    #pragma unroll
    for (int i = 0; i < 3; ++i) { float d = vals[i] - mean; ss += d * d; }
    float var = block_reduce_sum_256(ss) * (1.0f / D_EMB);
    float rstd = rsqrtf(var + 1e-5f);
    #pragma unroll
    for (int i = 0; i < 3; ++i) {
        int d = t + i * 256;
        store_val(y + (size_t)row * D_EMB + d, (vals[i] - mean) * rstd * g[d] + bta[d]);
    }
}

// ---------------- fused split-K reduce + residual + layernorm
template<typename OT>
__global__ __launch_bounds__(256)
void reduce_ln_kernel(const float* __restrict__ pbuf, float* __restrict__ z,
                      const float* __restrict__ g, const float* __restrict__ bta,
                      OT* __restrict__ y)
{
    int row = blockIdx.x;
    int t = threadIdx.x;
    const float* p0 = pbuf + (size_t)row * D_EMB;
    const float* p1 = pbuf + (size_t)MTOK * D_EMB + (size_t)row * D_EMB;
    float* zr = z + (size_t)row * D_EMB;
    float vals[3];
    float s = 0.f;
    #pragma unroll
    for (int i = 0; i < 3; ++i) {
        int d = t + i * 256;
        float v = zr[d] + p0[d] + p1[d];
        vals[i] = v;
        zr[d] = v;
        s += v;
    }
    float mean = block_reduce_sum_256(s) * (1.0f / D_EMB);
    float ss = 0.f;
    #pragma unroll
    for (int i = 0; i < 3; ++i) { float d = vals[i] - mean; ss += d * d; }
    float var = block_reduce_sum_256(ss) * (1.0f / D_EMB);
    float rstd = rsqrtf(var + 1e-5f);
    #pragma unroll
    for (int i = 0; i < 3; ++i) {
        int d = t + i * 256;
        store_val(y + (size_t)row * D_EMB + d, (vals[i] - mean) * rstd * g[d] + bta[d]);
    }
}

// ---------------- bf16 MFMA GEMM: 64x128 tile, BK=64, **8 waves (2x4)**.
// Same staging (global_load_lds w=16, rule-21 XOR swizzle, 2-buffer
// issue-early prefetch, strength-reduced addresses) and R6 M-slice XCD map
// as the proven R15/R17 kernel; only the wave decomposition changes:
// each wave owns a 32x32 sub-tile (acc[2][2], 8 MFMA/K-step) and staging is
// 3 issues/thread. LDS unchanged (48KB -> 3 blocks/CU) but waves/CU goes
// 9.4 -> 24: cross-block TLP hides each block's barrier-drain.
// EPI: 0 = none, 1 = exact gelu, 2 = add residual(fp32)
// SPLITK: grid.z = K-chunks; A/W advance by bz*K, C by bz*(gy*64)*N partials.
#define STAGE64(buf)                                                               \
    {                                                                              \
        __builtin_amdgcn_global_load_lds(                                          \
            (const __attribute__((address_space(1))) unsigned int*)gA0,            \
            (__attribute__((address_space(3))) unsigned int*)&As[buf][dS],         \
            16, 0, 0);                                                             \
        gA0 += 64;                                                                 \
        _Pragma("unroll")                                                          \
        for (int j = 0; j < 2; ++j) {                                              \
            __builtin_amdgcn_global_load_lds(                                      \
                (const __attribute__((address_space(1))) unsigned int*)gB[j],      \
                (__attribute__((address_space(3))) unsigned int*)&Bs[buf][j * 4096 + dS], \
                16, 0, 0);                                                         \
            gB[j] += 64;                                                           \
        }                                                                          \
    }

#define COMPUTE64(buf)                                                             \
    {                                                                              \
        bf16x8 a0[2], a1[2], b0[2], b1[2];                                         \
        _Pragma("unroll")                                                          \
        for (int m = 0; m < 2; ++m) {                                              \
            a0[m] = *(const bf16x8*)(&As[buf][rA[m] + x0]);                        \
            a1[m] = *(const bf16x8*)(&As[buf][rA[m] + x1]);                        \
        }                                                                          \
        _Pragma("unroll")                                                          \
        for (int n = 0; n < 2; ++n) {                                              \
            b0[n] = *(const bf16x8*)(&Bs[buf][rB[n] + x0]);                        \
            b1[n] = *(const bf16x8*)(&Bs[buf][rB[n] + x1]);                        \
        }                                                                          \
        _Pragma("unroll")                                                          \
        for (int m = 0; m < 2; ++m)                                                \
            _Pragma("unroll")                                                      \
            for (int n = 0; n < 2; ++n)                                            \
                acc[m][n] = __builtin_amdgcn_mfma_f32_16x16x32_bf16(a0[m], b0[n], acc[m][n], 0, 0, 0); \
        _Pragma("unroll")                                                          \
        for (int m = 0; m < 2; ++m)                                                \
            _Pragma("unroll")                                                      \
            for (int n = 0; n < 2; ++n)                                            \
                acc[m][n] = __builtin_amdgcn_mfma_f32_16x16x32_bf16(a1[m], b1[n], acc[m][n], 0, 0, 0); \
    }

template<int EPI, typename OT, bool SPLITK>
__global__ __launch_bounds__(512)
void mfma_gemm(const ushort* __restrict__ A, const ushort* __restrict__ W,
               OT* __restrict__ C, const float* __restrict__ res,
               int N, int K, int lda)
{
    __shared__ ushort As[2][64 * 64];
    __shared__ ushort Bs[2][128 * 64];

    int gx = gridDim.x, gy = gridDim.y;
    int bx = blockIdx.x, by = blockIdx.y;
    int bz = SPLITK ? blockIdx.z : 0;
    if ((gy & 7) == 0) {
        int flat = bx + gx * (by + gy * bz);
        int xcd = flat & 7, j = flat >> 3;
        int ry = gy >> 3;
        by = xcd * ry + (j % ry);
        int rem = j / ry;
        bx = rem % gx;
        bz = rem / gx;
    }
    int bm = by * 64, bn = bx * 128;

    const ushort* Ab = A + (size_t)bz * K;
    const ushort* Wb = W + (size_t)bz * K;
    OT* Cb = C + (SPLITK ? (size_t)bz * ((size_t)gy * 64) * N : 0);

    int tid = threadIdx.x;
    int w = tid >> 6, l = tid & 63;
    int wr = w >> 2, wc = w & 3;        // 2x4 wave grid; wave out = 32x32
    int lr = l & 15, lg = l >> 4;
    f32x4 acc[2][2] = {};

    // staging: 512 threads cover 64 rows x 8 col16 per issue.
    int srow = tid >> 3;                 // 0..63
    int pcol = tid & 7;
    int lcol8 = (pcol ^ (srow & 7)) << 3;   // (row+64)&7 == row&7
    int dS = srow * 64 + (pcol << 3);

    const ushort* gA0 = Ab + (size_t)(bm + srow) * lda + lcol8;
    const ushort* gB[2];
    #pragma unroll
    for (int j = 0; j < 2; ++j)
        gB[j] = Wb + (size_t)(bn + j * 64 + srow) * lda + lcol8;

    // compute-side constant offsets: fragment row&7 == lr&7
    int x0 = ((lg ^ (lr & 7)) << 3);
    int x1 = (((4 + lg) ^ (lr & 7)) << 3);
    int rA[2], rB[2];
    #pragma unroll
    for (int m = 0; m < 2; ++m) rA[m] = (wr * 32 + m * 16 + lr) * 64;
    #pragma unroll
    for (int n = 0; n < 2; ++n) rB[n] = (wc * 32 + n * 16 + lr) * 64;

    const int nk = K >> 6;          // even for all our shapes (12 or 24)
    STAGE64(0);
    __syncthreads();
    for (int t = 0; t < nk; t += 2) {
        STAGE64(1);                 // prefetch tile t+1 (flies during compute)
        COMPUTE64(0);               // compute tile t
        __syncthreads();
        if (t + 2 < nk) STAGE64(0); // prefetch tile t+2
        COMPUTE64(1);               // compute tile t+1
        __syncthreads();
    }

    int r0 = lg * 4;
    #pragma unroll
    for (int m = 0; m < 2; ++m) {
        #pragma unroll
        for (int n = 0; n < 2; ++n) {
            #pragma unroll
            for (int j = 0; j < 4; ++j) {
                int gm = bm + wr * 32 + m * 16 + r0 + j;
                int gn = bn + wc * 32 + n * 16 + lr;
                float v = acc[m][n][j];
                if (EPI == 1) v = 0.5f * v * (1.0f + erff(v * 0.70710678118654752f));
                if (EPI == 2) v += res[(size_t)gm * N + gn];
                store_val(Cb + (size_t)gm * N + gn, v);
            }
        }
    }
}

// ---------------- MFMA flash attention: one wave per 16-row q-tile (R10 form)
__global__ __launch_bounds__(256)
void attn_mfma_kernel(const ushort* __restrict__ qkv, ushort* __restrict__ o)
{
    int w = threadIdx.x >> 6, l = threadIdx.x & 63;
    int qt = blockIdx.x * 4 + w;
    int h = blockIdx.y, b = blockIdx.z;
    int q0 = qt * 16;
    int lr = l & 15, lg = l >> 4;

    const size_t rs = 3 * D_EMB;    // 2304
    const ushort* qbase = qkv + ((size_t)(b * NTOK)) * rs + h * HDIM;
    const ushort* kbase = qbase + D_EMB;
    const ushort* vbase = qbase + 2 * D_EMB;

    bf16x8 qf[2];
    qf[0] = *(const bf16x8*)(qbase + (size_t)(q0 + lr) * rs + lg * 8);
    qf[1] = *(const bf16x8*)(qbase + (size_t)(q0 + lr) * rs + 32 + lg * 8);

    f32x4 oacc[4] = {};
    float m_j[4], l_j[4];
    #pragma unroll
    for (int j = 0; j < 4; ++j) { m_j[j] = -1e30f; l_j[j] = 0.f; }

    __shared__ ushort P_lds[4][16][40];

    int ntiles = q0 / 32 + 1;
    for (int mt = 0; mt < ntiles; ++mt) {
        int m0 = mt * 32;
        f32x4 s[2] = {};
        #pragma unroll
        for (int kb = 0; kb < 2; ++kb) {
            const ushort* kr = kbase + (size_t)(m0 + kb * 16 + lr) * rs;
            bf16x8 k0 = *(const bf16x8*)(kr + lg * 8);
            bf16x8 k1 = *(const bf16x8*)(kr + 32 + lg * 8);
            s[kb] = __builtin_amdgcn_mfma_f32_16x16x32_bf16(qf[0], k0, s[kb], 0, 0, 0);
            s[kb] = __builtin_amdgcn_mfma_f32_16x16x32_bf16(qf[1], k1, s[kb], 0, 0, 0);
        }
        bool partial = (m0 + 31 > q0);
        float p[2][4], mx[4];
        #pragma unroll
        for (int j = 0; j < 4; ++j) {
            int qr = q0 + lg * 4 + j;
            float s0 = s[0][j] * 0.125f;
            float s1 = s[1][j] * 0.125f;
            if (partial) {
                if (m0 + lr > qr)      s0 = -1e30f;
                if (m0 + 16 + lr > qr) s1 = -1e30f;
            }
            p[0][j] = s0; p[1][j] = s1;
            float mm = fmaxf(s0, s1);
            mm = fmaxf(mm, __shfl_xor(mm, 1));
            mm = fmaxf(mm, __shfl_xor(mm, 2));
            mm = fmaxf(mm, __shfl_xor(mm, 4));
            mm = fmaxf(mm, __shfl_xor(mm, 8));
            mx[j] = mm;
        }
        #pragma unroll
        for (int j = 0; j < 4; ++j) {
            float mnew = fmaxf(m_j[j], mx[j]);
            float scale = __expf(m_j[j] - mnew);
            float p0 = __expf(p[0][j] - mnew);
            float p1 = __expf(p[1][j] - mnew);
            p[0][j] = p0; p[1][j] = p1;
            float rsum = p0 + p1;
            rsum += __shfl_xor(rsum, 1);
            rsum += __shfl_xor(rsum, 2);
            rsum += __shfl_xor(rsum, 4);
            rsum += __shfl_xor(rsum, 8);
            l_j[j] = l_j[j] * scale + rsum;
            m_j[j] = mnew;
            #pragma unroll
            for (int i = 0; i < 4; ++i) oacc[i][j] *= scale;
        }
        #pragma unroll
        for (int kb = 0; kb < 2; ++kb)
            #pragma unroll
            for (int j = 0; j < 4; ++j)
                P_lds[w][lg * 4 + j][kb * 16 + lr] = f2bf(p[kb][j]);
        asm volatile("s_waitcnt lgkmcnt(0)" ::: "memory");
        bf16x8 pa = *(const bf16x8*)(&P_lds[w][lr][lg * 8]);
        #pragma unroll
        for (int i = 0; i < 4; ++i) {
            bf16x8 vf;
            const ushort* vp = vbase + (size_t)(m0 + lg * 8) * rs + i * 16 + lr;
            #pragma unroll
            for (int j = 0; j < 8; ++j) vf[j] = (short)vp[(size_t)j * rs];
            oacc[i] = __builtin_amdgcn_mfma_f32_16x16x32_bf16(pa, vf, oacc[i], 0, 0, 0);
        }
    }
    #pragma unroll
    for (int i = 0; i < 4; ++i) {
        #pragma unroll
        for (int j = 0; j < 4; ++j) {
            int qr = q0 + lg * 4 + j;
            int d  = i * 16 + lr;
            float v = oacc[i][j] / l_j[j];
            o[((size_t)(b * NTOK + qr)) * D_EMB + h * HDIM + d] = f2bf(v);
        }
    }
}

// ---------------- mean over tokens
__global__ void mean_kernel(const float* __restrict__ x, float* __restrict__ enc)
{
    int b = blockIdx.x; int d = threadIdx.x;    // 768 threads
    float s = 0.f;
    for (int n = 0; n < NTOK; ++n) s += x[((size_t)(b * NTOK + n)) * D_EMB + d];
    enc[b * D_EMB + d] = s * (1.0f / NTOK);
}

// ---------------- heads
__global__ void head1_kernel(const float* __restrict__ enc, const float* __restrict__ w,
                             const float* __restrict__ bias, float* __restrict__ r)
{
    int b = blockIdx.x; int j = threadIdx.x;    // 384 threads
    float acc = bias[j];
    const float* e = enc + b * D_EMB;
    const float* wr = w + (size_t)j * D_EMB;
    for (int k = 0; k < D_EMB; ++k) acc += e[k] * wr[k];
    r[b * 384 + j] = fmaxf(acc, 0.f);
}

__global__ void head2_kernel(const float* __restrict__ r, const float* __restrict__ w,
                             const float* __restrict__ bias, float* __restrict__ out)
{
    int idx = threadIdx.x;
    if (idx >= 16) return;
    int b = idx >> 1, j = idx & 1;
    float acc = bias[j];
    for (int k = 0; k < 384; ++k) acc += r[b * 384 + k] * w[j * 384 + k];
    out[b * 2 + j] = acc;
}

extern "C" void kernel_launch(void* const* d_in, const int* in_sizes, int n_in,
                              void* d_out, int out_size, void* d_ws, size_t ws_size,
                              hipStream_t stream)
{
    const float* x     = (const float*)d_in[0];
    const float* pp_w  = (const float*)d_in[1];
    const float* pp_b  = (const float*)d_in[2];
    const float* pe    = (const float*)d_in[3];
    const float* ln1_g = (const float*)d_in[4];
    const float* ln1_b = (const float*)d_in[5];
    const float* qkv_w = (const float*)d_in[6];
    const float* out_w = (const float*)d_in[7];
    const float* ln2_g = (const float*)d_in[8];
    const float* ln2_b = (const float*)d_in[9];
    const float* fc1_w = (const float*)d_in[10];
    const float* fc2_w = (const float*)d_in[11];
    const float* lnf_g = (const float*)d_in[12];
    const float* lnf_b = (const float*)d_in[13];
    const float* h1_w  = (const float*)d_in[14];
    const float* h1_b  = (const float*)d_in[15];
    const float* h2_w  = (const float*)d_in[16];
    const float* h2_b  = (const float*)d_in[17];
    float* out = (float*)d_out;

    const int nq = 3 * D_EMB * D_EMB, no = D_EMB * D_EMB, nf = DFF * D_EMB;
    const size_t per_layer_w = ((size_t)nq + no + 2 * nf) * 2;   // bytes

    char* p = (char*)d_ws;
    float*  z      = (float*)p;  p += (size_t)MTOK * D_EMB * 4;
    ushort* big_bf = (ushort*)p; p += (size_t)MTOK * DFF * 2;
    ushort* h_bf   = (ushort*)p; p += (size_t)MTOK * D_EMB * 2;
    float*  pbuf   = (float*)p;  p += (size_t)2 * MTOK * D_EMB * 4;
    float*  enc    = (float*)p;  p += BATCH * D_EMB * 4;
    float*  r1     = (float*)p;  p += BATCH * 384 * 4;
    size_t base_used = (size_t)(p - (char*)d_ws);
    bool full = (ws_size >= base_used + NLAYER * per_layer_w);
    int nlw = full ? NLAYER : 1;
    ushort* wq_bf  = (ushort*)p; p += (size_t)nlw * nq * 2;
    ushort* wo_bf  = (ushort*)p; p += (size_t)nlw * no * 2;
    ushort* wf1_bf = (ushort*)p; p += (size_t)nlw * nf * 2;
    ushort* wf2_bf = (ushort*)p; p += (size_t)nlw * nf * 2;
    float*  lnf_out = (float*)big_bf;   // reuse

    patch_embed_kernel<<<MTOK, 256, 0, stream>>>(x, pp_w, pp_b, pe, z);

    if (full) {
        long long tq = (long long)NLAYER * nq / 4, to = (long long)NLAYER * no / 4;
        long long tf = (long long)NLAYER * nf / 4;
        long long tot = tq + to + 2 * tf;
        f2bf4_kernel<<<(int)((tot + 255) / 256), 256, 0, stream>>>(
            qkv_w, wq_bf, (int)tq, out_w, wo_bf, (int)to,
            fc1_w, wf1_bf, (int)tf, fc2_w, wf2_bf, (int)tf);
    }

    // ln1 of layer 0 (later layers get it fused into reduce_ln)
    ln_kernel<ushort><<<MTOK, 256, 0, stream>>>(z, ln1_g, ln1_b, h_bf);

    const int cvt_blocks = (nq / 4 + no / 4 + 2 * (nf / 4) + 255) / 256;

    for (int i = 0; i < NLAYER; ++i) {
        const ushort* wq  = wq_bf  + (full ? (size_t)i * nq : 0);
        const ushort* wo  = wo_bf  + (full ? (size_t)i * no : 0);
        const ushort* wf1 = wf1_bf + (full ? (size_t)i * nf : 0);
        const ushort* wf2 = wf2_bf + (full ? (size_t)i * nf : 0);
        if (!full) {
            f2bf4_kernel<<<cvt_blocks, 256, 0, stream>>>(
                qkv_w + (size_t)i * nq, wq_bf,  nq / 4,
                out_w + (size_t)i * no, wo_bf,  no / 4,
                fc1_w + (size_t)i * nf, wf1_bf, nf / 4,
                fc2_w + (size_t)i * nf, wf2_bf, nf / 4);
        }

        dim3 gq((3 * D_EMB) / 128, MTOK / 64);
        mfma_gemm<0, ushort, false><<<gq, 512, 0, stream>>>(h_bf, wq, big_bf, nullptr,
                                                            3 * D_EMB, D_EMB, D_EMB);

        dim3 ga(NTOK / 64, NHEAD, BATCH);
        attn_mfma_kernel<<<ga, 256, 0, stream>>>(big_bf, h_bf);

        dim3 gp(D_EMB / 128, MTOK / 64);
        mfma_gemm<2, float, false><<<gp, 512, 0, stream>>>(h_bf, wo, z, z,
                                                           D_EMB, D_EMB, D_EMB);

        ln_kernel<ushort><<<MTOK, 256, 0, stream>>>(z, ln2_g + i * D_EMB, ln2_b + i * D_EMB, h_bf);

        dim3 g1(DFF / 128, MTOK / 64);
        mfma_gemm<1, ushort, false><<<g1, 512, 0, stream>>>(h_bf, wf1, big_bf, nullptr,
                                                            DFF, D_EMB, D_EMB);

        dim3 g2(D_EMB / 128, MTOK / 64, 2);
        mfma_gemm<0, float, true><<<g2, 512, 0, stream>>>(big_bf, wf2, pbuf, nullptr,
                                                          D_EMB, DFF / 2, DFF);

        if (i < NLAYER - 1) {
            reduce_ln_kernel<ushort><<<MTOK, 256, 0, stream>>>(
                pbuf, z, ln1_g + (i + 1) * D_EMB, ln1_b + (i + 1) * D_EMB, h_bf);
        } else {
            reduce_ln_kernel<float><<<MTOK, 256, 0, stream>>>(
                pbuf, z, lnf_g, lnf_b, lnf_out);
        }
    }

    mean_kernel<<<BATCH, D_EMB, 0, stream>>>(lnf_out, enc);
    head1_kernel<<<BATCH, 384, 0, stream>>>(enc, h1_w, h1_b, r1);
    head2_kernel<<<1, 64, 0, stream>>>(r1, h2_w, h2_b, out);
}